// Round 4
// baseline (232.066 us; speedup 1.0000x reference)
//
#include <hip/hip_runtime.h>
#include <math.h>

typedef float f4 __attribute__((ext_vector_type(4)));

static __device__ __forceinline__ void stnt(float* p, f4 v) {
    __builtin_nontemporal_store(v, (f4*)p);
}

// x: [B=4][A=64][S=64][C=64][F=64] fp32.
// out = x * att_c[b,c,f] * att_s[b,s,f] * att_a[b,a,f]

// ---------------- pool: grid 1024 = (b,a,q), block 256 (4 waves) ----------------
// wave w covers s = q*16 + w*4 + r (r=0..3). Outputs:
//   ps[b][a][s][f] (sum over c, 4 MiB), pc[(b,a,q)][c][f] (sum over 16 s, 16 MiB)
__global__ __launch_bounds__(256, 4) void pool_kernel(
    const float* __restrict__ x,
    float* __restrict__ ps,
    float* __restrict__ pc)
{
    const int blk = blockIdx.x;       // ba*4 + q
    const int q  = blk & 3;
    const int ba = blk >> 2;
    const int t  = threadIdx.x;
    const int w  = t >> 6, lane = t & 63;
    const int fg = lane & 15;         // f = fg*4
    const int cg = lane >> 4;         // c-quarter

    const float* xa = x + (size_t)ba * 262144;

    f4 csum[16];
#pragma unroll
    for (int j = 0; j < 16; ++j) csum[j] = f4{0.f, 0.f, 0.f, 0.f};

#pragma unroll
    for (int r = 0; r < 4; ++r) {
        const int s = q * 16 + w * 4 + r;
        const float* xs = xa + s * 4096 + cg * 1024 + fg * 4;
        f4 ssum = f4{0.f, 0.f, 0.f, 0.f};
#pragma unroll
        for (int j = 0; j < 16; ++j) {
            f4 v = *(const f4*)(xs + j * 64);
            ssum += v;
            csum[j] += v;
        }
        // butterfly over cg lane bits: full sum over 64 c
#pragma unroll
        for (int i = 0; i < 4; ++i) ssum[i] += __shfl_xor(ssum[i], 16);
#pragma unroll
        for (int i = 0; i < 4; ++i) ssum[i] += __shfl_xor(ssum[i], 32);
        if (cg == 0)
            *(f4*)(ps + (size_t)ba * 4096 + s * 64 + fg * 4) = ssum;
    }

    // log-depth 4->1 wave merge, 32 KiB LDS
    __shared__ float lds[2][4096];
    if (w >= 2) {
#pragma unroll
        for (int j = 0; j < 16; ++j)
            *(f4*)(&lds[w - 2][(cg * 16 + j) * 64 + fg * 4]) = csum[j];
    }
    __syncthreads();
    if (w < 2) {
#pragma unroll
        for (int j = 0; j < 16; ++j)
            csum[j] += *(const f4*)(&lds[w][(cg * 16 + j) * 64 + fg * 4]);
    }
    __syncthreads();
    if (w == 1) {
#pragma unroll
        for (int j = 0; j < 16; ++j)
            *(f4*)(&lds[0][(cg * 16 + j) * 64 + fg * 4]) = csum[j];
    }
    __syncthreads();
    if (w == 0) {
        float* dst = pc + (size_t)blk * 4096;
#pragma unroll
        for (int j = 0; j < 16; ++j) {
            f4 o = *(const f4*)(&lds[0][(cg * 16 + j) * 64 + fg * 4]);
            *(f4*)(dst + (cg * 16 + j) * 64 + fg * 4) = csum[j] + o;
        }
    }
}

// ---------------- reduce: grid 768 = region*256 + b*64 + d, block 256 ----------------
// region 0: m_c (heavy), 1: m_s, 2: m_a. Wave-coalesced 256 B rows, g-split.
__global__ __launch_bounds__(256) void reduce_kernel(
    const float* __restrict__ ps, const float* __restrict__ pc,
    float* __restrict__ m_a, float* __restrict__ m_s, float* __restrict__ m_c)
{
    const int blk = blockIdx.x;
    const int region = blk >> 8;
    const int b = (blk >> 6) & 3;
    const int d = blk & 63;
    const int t = threadIdx.x;
    const int g = t >> 6, f = t & 63;

    float acc = 0.f;
    if (region == 0) {
#pragma unroll 8
        for (int i = g; i < 256; i += 4)
            acc += pc[(size_t)(b * 256 + i) * 4096 + d * 64 + f];
    } else if (region == 1) {
#pragma unroll 8
        for (int i = g; i < 64; i += 4)          // m_s: sum over a
            acc += ps[((size_t)(b * 64 + i) * 64 + d) * 64 + f];
    } else {
#pragma unroll 8
        for (int i = g; i < 64; i += 4)          // m_a: sum over s
            acc += ps[((size_t)(b * 64 + d) * 64 + i) * 64 + f];
    }

    __shared__ float sm[4][64];
    sm[g][f] = acc;
    __syncthreads();
    if (t < 64) {
        float tot = (sm[0][t] + sm[1][t] + sm[2][t] + sm[3][t]) * (1.f / 4096.f);
        float* dst = region == 0 ? m_c : (region == 1 ? m_s : m_a);
        dst[((size_t)b * 64 + d) * 64 + t] = tot;
    }
}

// ---------------- attn: grid 192 = (axis,f), block 64, all 4 batches ----------------
__global__ __launch_bounds__(64) void attn_kernel(
    const float* __restrict__ m_a, const float* __restrict__ m_s, const float* __restrict__ m_c,
    const float* __restrict__ w1_a, const float* __restrict__ w1_s, const float* __restrict__ w1_c,
    const float* __restrict__ w2_a, const float* __restrict__ w2_s, const float* __restrict__ w2_c,
    float* __restrict__ att_a, float* __restrict__ att_s, float* __restrict__ att_c)
{
    const int axis = blockIdx.x >> 6;
    const int f    = blockIdx.x & 63;
    const float* m  = axis == 0 ? m_a  : (axis == 1 ? m_s  : m_c);
    const float* w1 = axis == 0 ? w1_a : (axis == 1 ? w1_s : w1_c);  // [F,64,16]
    const float* w2 = axis == 0 ? w2_a : (axis == 1 ? w2_s : w2_c);  // [F,16,64]
    float* att      = axis == 0 ? att_a : (axis == 1 ? att_s : att_c);

    __shared__ float w1ld[1024];
    __shared__ float w2ld[1024];
    __shared__ float mld[4][64];
    __shared__ float zld[4][16];
    const int t = threadIdx.x;

    {
        const f4* s1 = (const f4*)(w1 + (size_t)f * 1024);
        const f4* s2 = (const f4*)(w2 + (size_t)f * 1024);
#pragma unroll
        for (int i = 0; i < 4; ++i) {
            ((f4*)w1ld)[t + 64 * i] = s1[t + 64 * i];
            ((f4*)w2ld)[t + 64 * i] = s2[t + 64 * i];
        }
#pragma unroll
        for (int bb = 0; bb < 4; ++bb)
            mld[bb][t] = m[((size_t)bb * 64 + t) * 64 + f];
    }
    __syncthreads();
    {
        const int bb = t >> 4, e = t & 15;       // 4 b x 16 e = 64 threads
        float acc = 0.f;
#pragma unroll
        for (int dd = 0; dd < 64; ++dd) acc += mld[bb][dd] * w1ld[dd * 16 + e];
        zld[bb][e] = fmaxf(acc, 0.f);
    }
    __syncthreads();
#pragma unroll
    for (int bb = 0; bb < 4; ++bb) {
        float acc = 0.f;
#pragma unroll
        for (int e = 0; e < 16; ++e) acc += zld[bb][e] * w2ld[e * 64 + t];
        att[((size_t)bb * 64 + t) * 64 + f] = 1.f / (1.f + expf(-acc));
    }
}

// ---------------- scale: grid 2048 (reversed), block 256 ----------------
__global__ __launch_bounds__(256) void scale_kernel(
    const float* __restrict__ x,
    const float* __restrict__ att_a, const float* __restrict__ att_s,
    const float* __restrict__ att_c,
    float* __restrict__ out)
{
    const int blk = 2047 - blockIdx.x;  // start at b=3: tail of pool's read stream
    const int so = blk & 7;
    const int a  = (blk >> 3) & 63;
    const int b  = blk >> 9;
    const int t  = threadIdx.x;
    const int fg = t & 15;
    const int cq = t >> 4;

    __shared__ float acl[64][68];   // +4 pad: conflict-free column reads
    __shared__ float asl[8][64];

    {
        const f4* srcc = (const f4*)(att_c + (size_t)b * 4096);
#pragma unroll
        for (int i = 0; i < 4; ++i) {
            int qq = t + 256 * i;                 // f4 id: c = qq>>4, f = (qq&15)*4
            f4 v = srcc[qq];
            *(f4*)(&acl[qq >> 4][(qq & 15) * 4]) = v;
        }
        if (t < 128) {
            f4 v = *(const f4*)(att_s + (size_t)b * 4096 + so * 512 + t * 4);
            *(f4*)(&asl[t >> 4][(t & 15) * 4]) = v;
        }
    }
    f4 aa = *(const f4*)(att_a + (size_t)b * 4096 + a * 64 + fg * 4);
    __syncthreads();

    f4 acv[4];
#pragma unroll
    for (int k = 0; k < 4; ++k)
        acv[k] = *(const f4*)(&acl[k * 16 + cq][fg * 4]);

    const size_t base = (size_t)(b * 4096 + a * 64 + so * 8) * 4096;
    const float* xs = x + base;
    float* os = out + base;

    for (int sl = 0; sl < 8; ++sl) {
        f4 m0 = aa * *(const f4*)(&asl[sl][fg * 4]);
#pragma unroll
        for (int k = 0; k < 4; ++k) {
            const int c = k * 16 + cq;
            const size_t off = (size_t)(sl * 64 + c) * 64 + fg * 4;
            f4 v = *(const f4*)(xs + off);
            stnt(os + off, v * m0 * acv[k]);
        }
    }
}

extern "C" void kernel_launch(void* const* d_in, const int* in_sizes, int n_in,
                              void* d_out, int out_size, void* d_ws, size_t ws_size,
                              hipStream_t stream)
{
    (void)in_sizes; (void)n_in; (void)out_size; (void)ws_size;
    const float* x    = (const float*)d_in[0];
    const float* w1_a = (const float*)d_in[1];
    const float* w1_s = (const float*)d_in[2];
    const float* w1_c = (const float*)d_in[3];
    const float* w2_a = (const float*)d_in[4];
    const float* w2_s = (const float*)d_in[5];
    const float* w2_c = (const float*)d_in[6];
    float* out = (float*)d_out;

    // Workspace layout (all fully rewritten each call before being read):
    float* ps    = (float*)d_ws;            // [4][64][64][64]   4 MiB
    float* pc    = ps + 1048576;            // [1024][64][64]   16 MiB
    float* m_a   = pc + 4194304;            // [4][64][64]      64 KiB each
    float* m_s   = m_a + 16384;
    float* m_c   = m_s + 16384;
    float* att_a = m_c + 16384;
    float* att_s = att_a + 16384;
    float* att_c = att_s + 16384;

    hipLaunchKernelGGL(pool_kernel,   dim3(1024), dim3(256), 0, stream, x, ps, pc);
    hipLaunchKernelGGL(reduce_kernel, dim3(768),  dim3(256), 0, stream,
                       ps, pc, m_a, m_s, m_c);
    hipLaunchKernelGGL(attn_kernel,   dim3(192),  dim3(64),  0, stream,
                       m_a, m_s, m_c, w1_a, w1_s, w1_c, w2_a, w2_s, w2_c,
                       att_a, att_s, att_c);
    hipLaunchKernelGGL(scale_kernel,  dim3(2048), dim3(256), 0, stream,
                       x, att_a, att_s, att_c, out);
}

// Round 5
// 144.747 us; speedup vs baseline: 1.6033x; 1.6033x over previous
//
#include <hip/hip_runtime.h>
#include <math.h>

typedef float f4 __attribute__((ext_vector_type(4)));

static __device__ __forceinline__ void stnt(float* p, f4 v) {
    __builtin_nontemporal_store(v, (f4*)p);
}

// x: [B=4][A=64][S=64][C=64][F=64] fp32.
// out = x * att_c[b,c,f] * att_s[b,s,f] * att_a[b,a,f]

// ---------------- pool: grid 1024 = (b,a,q), block 256 (4 waves) ----------------
// wave w covers s = q*16 + w*4 + r (r=0..3). Outputs:
//   ps[b][a][s][f] (sum over c, 4 MiB), pc[(b,a,q)][c][f] (sum over 16 s, 16 MiB)
// NOTE: no min-waves bound — csum[16] needs ~64 VGPRs; capping to 64 total
// spilled to scratch (R4: WRITE_SIZE 190 MB vs 20 MiB expected, 168 us).
__global__ __launch_bounds__(256) void pool_kernel(
    const float* __restrict__ x,
    float* __restrict__ ps,
    float* __restrict__ pc)
{
    const int blk = blockIdx.x;       // ba*4 + q
    const int q  = blk & 3;
    const int ba = blk >> 2;
    const int t  = threadIdx.x;
    const int w  = t >> 6, lane = t & 63;
    const int fg = lane & 15;         // f = fg*4
    const int cg = lane >> 4;         // c-quarter

    const float* xa = x + (size_t)ba * 262144;

    f4 csum[16];
#pragma unroll
    for (int j = 0; j < 16; ++j) csum[j] = f4{0.f, 0.f, 0.f, 0.f};

#pragma unroll
    for (int r = 0; r < 4; ++r) {
        const int s = q * 16 + w * 4 + r;
        const float* xs = xa + s * 4096 + cg * 1024 + fg * 4;
        f4 ssum = f4{0.f, 0.f, 0.f, 0.f};
#pragma unroll
        for (int j = 0; j < 16; ++j) {
            f4 v = *(const f4*)(xs + j * 64);
            ssum += v;
            csum[j] += v;
        }
        // butterfly over cg lane bits: full sum over 64 c
#pragma unroll
        for (int i = 0; i < 4; ++i) ssum[i] += __shfl_xor(ssum[i], 16);
#pragma unroll
        for (int i = 0; i < 4; ++i) ssum[i] += __shfl_xor(ssum[i], 32);
        if (cg == 0)
            *(f4*)(ps + (size_t)ba * 4096 + s * 64 + fg * 4) = ssum;
    }

    // log-depth 4->1 wave merge, 32 KiB LDS
    __shared__ float lds[2][4096];
    if (w >= 2) {
#pragma unroll
        for (int j = 0; j < 16; ++j)
            *(f4*)(&lds[w - 2][(cg * 16 + j) * 64 + fg * 4]) = csum[j];
    }
    __syncthreads();
    if (w < 2) {
#pragma unroll
        for (int j = 0; j < 16; ++j)
            csum[j] += *(const f4*)(&lds[w][(cg * 16 + j) * 64 + fg * 4]);
    }
    __syncthreads();
    if (w == 1) {
#pragma unroll
        for (int j = 0; j < 16; ++j)
            *(f4*)(&lds[0][(cg * 16 + j) * 64 + fg * 4]) = csum[j];
    }
    __syncthreads();
    if (w == 0) {
        float* dst = pc + (size_t)blk * 4096;
#pragma unroll
        for (int j = 0; j < 16; ++j) {
            f4 o = *(const f4*)(&lds[0][(cg * 16 + j) * 64 + fg * 4]);
            *(f4*)(dst + (cg * 16 + j) * 64 + fg * 4) = csum[j] + o;
        }
    }
}

// ---------------- reduce: grid 768 = region*256 + b*64 + d, block 256 ----------------
// region 0: m_c (heavy), 1: m_s, 2: m_a. Wave-coalesced 256 B rows, g-split.
__global__ __launch_bounds__(256) void reduce_kernel(
    const float* __restrict__ ps, const float* __restrict__ pc,
    float* __restrict__ m_a, float* __restrict__ m_s, float* __restrict__ m_c)
{
    const int blk = blockIdx.x;
    const int region = blk >> 8;
    const int b = (blk >> 6) & 3;
    const int d = blk & 63;
    const int t = threadIdx.x;
    const int g = t >> 6, f = t & 63;

    float acc = 0.f;
    if (region == 0) {
#pragma unroll 8
        for (int i = g; i < 256; i += 4)
            acc += pc[(size_t)(b * 256 + i) * 4096 + d * 64 + f];
    } else if (region == 1) {
#pragma unroll 8
        for (int i = g; i < 64; i += 4)          // m_s: sum over a
            acc += ps[((size_t)(b * 64 + i) * 64 + d) * 64 + f];
    } else {
#pragma unroll 8
        for (int i = g; i < 64; i += 4)          // m_a: sum over s
            acc += ps[((size_t)(b * 64 + d) * 64 + i) * 64 + f];
    }

    __shared__ float sm[4][64];
    sm[g][f] = acc;
    __syncthreads();
    if (t < 64) {
        float tot = (sm[0][t] + sm[1][t] + sm[2][t] + sm[3][t]) * (1.f / 4096.f);
        float* dst = region == 0 ? m_c : (region == 1 ? m_s : m_a);
        dst[((size_t)b * 64 + d) * 64 + t] = tot;
    }
}

// ---------------- attn: grid 192 = (axis,f), block 64, all 4 batches ----------------
__global__ __launch_bounds__(64) void attn_kernel(
    const float* __restrict__ m_a, const float* __restrict__ m_s, const float* __restrict__ m_c,
    const float* __restrict__ w1_a, const float* __restrict__ w1_s, const float* __restrict__ w1_c,
    const float* __restrict__ w2_a, const float* __restrict__ w2_s, const float* __restrict__ w2_c,
    float* __restrict__ att_a, float* __restrict__ att_s, float* __restrict__ att_c)
{
    const int axis = blockIdx.x >> 6;
    const int f    = blockIdx.x & 63;
    const float* m  = axis == 0 ? m_a  : (axis == 1 ? m_s  : m_c);
    const float* w1 = axis == 0 ? w1_a : (axis == 1 ? w1_s : w1_c);  // [F,64,16]
    const float* w2 = axis == 0 ? w2_a : (axis == 1 ? w2_s : w2_c);  // [F,16,64]
    float* att      = axis == 0 ? att_a : (axis == 1 ? att_s : att_c);

    __shared__ float w1ld[1024];
    __shared__ float w2ld[1024];
    __shared__ float mld[4][64];
    __shared__ float zld[4][16];
    const int t = threadIdx.x;

    {
        const f4* s1 = (const f4*)(w1 + (size_t)f * 1024);
        const f4* s2 = (const f4*)(w2 + (size_t)f * 1024);
#pragma unroll
        for (int i = 0; i < 4; ++i) {
            ((f4*)w1ld)[t + 64 * i] = s1[t + 64 * i];
            ((f4*)w2ld)[t + 64 * i] = s2[t + 64 * i];
        }
#pragma unroll
        for (int bb = 0; bb < 4; ++bb)
            mld[bb][t] = m[((size_t)bb * 64 + t) * 64 + f];
    }
    __syncthreads();
    {
        const int bb = t >> 4, e = t & 15;       // 4 b x 16 e = 64 threads
        float acc = 0.f;
#pragma unroll
        for (int dd = 0; dd < 64; ++dd) acc += mld[bb][dd] * w1ld[dd * 16 + e];
        zld[bb][e] = fmaxf(acc, 0.f);
    }
    __syncthreads();
#pragma unroll
    for (int bb = 0; bb < 4; ++bb) {
        float acc = 0.f;
#pragma unroll
        for (int e = 0; e < 16; ++e) acc += zld[bb][e] * w2ld[e * 64 + t];
        att[((size_t)bb * 64 + t) * 64 + f] = 1.f / (1.f + expf(-acc));
    }
}

// ---------------- scale: grid 2048 (reversed), block 256 ----------------
__global__ __launch_bounds__(256) void scale_kernel(
    const float* __restrict__ x,
    const float* __restrict__ att_a, const float* __restrict__ att_s,
    const float* __restrict__ att_c,
    float* __restrict__ out)
{
    const int blk = 2047 - blockIdx.x;  // start at b=3: tail of pool's read stream
    const int so = blk & 7;
    const int a  = (blk >> 3) & 63;
    const int b  = blk >> 9;
    const int t  = threadIdx.x;
    const int fg = t & 15;
    const int cq = t >> 4;

    __shared__ float acl[64][68];   // +4 pad: conflict-free column reads
    __shared__ float asl[8][64];

    {
        const f4* srcc = (const f4*)(att_c + (size_t)b * 4096);
#pragma unroll
        for (int i = 0; i < 4; ++i) {
            int qq = t + 256 * i;                 // f4 id: c = qq>>4, f = (qq&15)*4
            f4 v = srcc[qq];
            *(f4*)(&acl[qq >> 4][(qq & 15) * 4]) = v;
        }
        if (t < 128) {
            f4 v = *(const f4*)(att_s + (size_t)b * 4096 + so * 512 + t * 4);
            *(f4*)(&asl[t >> 4][(t & 15) * 4]) = v;
        }
    }
    f4 aa = *(const f4*)(att_a + (size_t)b * 4096 + a * 64 + fg * 4);
    __syncthreads();

    f4 acv[4];
#pragma unroll
    for (int k = 0; k < 4; ++k)
        acv[k] = *(const f4*)(&acl[k * 16 + cq][fg * 4]);

    const size_t base = (size_t)(b * 4096 + a * 64 + so * 8) * 4096;
    const float* xs = x + base;
    float* os = out + base;

    for (int sl = 0; sl < 8; ++sl) {
        f4 m0 = aa * *(const f4*)(&asl[sl][fg * 4]);
#pragma unroll
        for (int k = 0; k < 4; ++k) {
            const int c = k * 16 + cq;
            const size_t off = (size_t)(sl * 64 + c) * 64 + fg * 4;
            f4 v = *(const f4*)(xs + off);
            stnt(os + off, v * m0 * acv[k]);
        }
    }
}

extern "C" void kernel_launch(void* const* d_in, const int* in_sizes, int n_in,
                              void* d_out, int out_size, void* d_ws, size_t ws_size,
                              hipStream_t stream)
{
    (void)in_sizes; (void)n_in; (void)out_size; (void)ws_size;
    const float* x    = (const float*)d_in[0];
    const float* w1_a = (const float*)d_in[1];
    const float* w1_s = (const float*)d_in[2];
    const float* w1_c = (const float*)d_in[3];
    const float* w2_a = (const float*)d_in[4];
    const float* w2_s = (const float*)d_in[5];
    const float* w2_c = (const float*)d_in[6];
    float* out = (float*)d_out;

    // Workspace layout (all fully rewritten each call before being read):
    float* ps    = (float*)d_ws;            // [4][64][64][64]   4 MiB
    float* pc    = ps + 1048576;            // [1024][64][64]   16 MiB
    float* m_a   = pc + 4194304;            // [4][64][64]      64 KiB each
    float* m_s   = m_a + 16384;
    float* m_c   = m_s + 16384;
    float* att_a = m_c + 16384;
    float* att_s = att_a + 16384;
    float* att_c = att_s + 16384;

    hipLaunchKernelGGL(pool_kernel,   dim3(1024), dim3(256), 0, stream, x, ps, pc);
    hipLaunchKernelGGL(reduce_kernel, dim3(768),  dim3(256), 0, stream,
                       ps, pc, m_a, m_s, m_c);
    hipLaunchKernelGGL(attn_kernel,   dim3(192),  dim3(64),  0, stream,
                       m_a, m_s, m_c, w1_a, w1_s, w1_c, w2_a, w2_s, w2_c,
                       att_a, att_s, att_c);
    hipLaunchKernelGGL(scale_kernel,  dim3(2048), dim3(256), 0, stream,
                       x, att_a, att_s, att_c, out);
}